// Round 2
// baseline (10520.696 us; speedup 1.0000x reference)
//
#include <hip/hip_runtime.h>
#include <hip/hip_bf16.h>

typedef unsigned int u32;
typedef unsigned short u16;
using short8 = __attribute__((ext_vector_type(8))) short;
using f32x4  = __attribute__((ext_vector_type(4))) float;

#define B_    64
#define T_    512
#define INP_  128
#define REC_  1024
#define OUT_  64
#define NSTEP 511
#define R_STRIDE_B ((size_t)T_ * REC_)   // 524288 floats per batch in r region

// ---- ws layout (bytes) ----
#define OFF_WRH   0u
#define OFF_WRL   2097152u
#define OFF_WIH   4194304u
#define OFF_WIL   4456448u
#define OFF_WOH   4718592u
#define OFF_WOL   4849664u
#define OFF_BSUM  4980736u
#define OFF_RBUF  4984832u           // u32[2][64*1024] = 524288 B
#define OFF_FLAGS 5509120u           // u32[256] dense (wave-slice*64 + wg)
#define SYNC_BYTES (524288u + 1024u)

__device__ __forceinline__ u16 bf16h(float x) {
  u32 u = __float_as_uint(x);
  u32 r = (u + 0x7fffu + ((u >> 16) & 1u)) >> 16;
  return (u16)r;
}
__device__ __forceinline__ float bf16f(u16 h) {
  return __uint_as_float(((u32)h) << 16);
}
__device__ __forceinline__ f32x4 mfma16(short8 a, short8 b, f32x4 c) {
  return __builtin_amdgcn_mfma_f32_16x16x32_bf16(a, b, c, 0, 0, 0);
}
__device__ __forceinline__ void split8(const float* x, short8& ah, short8& al) {
  #pragma unroll
  for (int e = 0; e < 8; ++e) {
    u16 h = bf16h(x[e]);
    ah[e] = (short)h;
    al[e] = (short)bf16h(x[e] - bf16f(h));
  }
}

// ---------- Phase 0: pack weights into bf16 hi/lo planes ----------
__global__ void pack_w(const float* __restrict__ Wr, const float* __restrict__ Wi,
                       const float* __restrict__ Wo, const float* __restrict__ bi,
                       const float* __restrict__ br,
                       u16* WrH, u16* WrL, u16* WiH, u16* WiL, u16* WoH, u16* WoL,
                       float* bsum) {
  int id = blockIdx.x * 256 + threadIdx.x;
  if (id < REC_ * REC_) { float x = Wr[id]; u16 h = bf16h(x); WrH[id] = h; WrL[id] = bf16h(x - bf16f(h)); }
  if (id < REC_ * INP_) { float x = Wi[id]; u16 h = bf16h(x); WiH[id] = h; WiL[id] = bf16h(x - bf16f(h)); }
  if (id < OUT_ * REC_) { float x = Wo[id]; u16 h = bf16h(x); WoH[id] = h; WoL[id] = bf16h(x - bf16f(h)); }
  if (id < REC_) bsum[id] = bi[id] + br[id];
}

// ---------- Phase 1: drive[b][t][j] -> rOut (in-place in d_out r region) ----------
// drive = inp@Wi^T + bi + br + 0.1*noise[t];  t==0 rows get 0 (r0).
__global__ __launch_bounds__(256) void rnn_phase1(
    const float* __restrict__ inp, const float* __restrict__ noise,
    const u16* __restrict__ WiH, const u16* __restrict__ WiL,
    const float* __restrict__ bsum, float* __restrict__ rOut)
{
  const int bid = blockIdx.x;          // 8192 = 512 m-tiles * 16 n-tiles
  const int mt = bid >> 4, nt4 = bid & 15;
  const int tid = threadIdx.x, wave = tid >> 6, lane = tid & 63;
  const int l15 = lane & 15, lk = lane >> 4;
  const int m0 = mt * 64 + wave * 16;
  const int n0 = nt4 * 64;
  const int arow = m0 + l15;
  const float* ap = inp + (size_t)arow * INP_ + lk * 8;

  short8 ah[4], al[4];
  #pragma unroll
  for (int s = 0; s < 4; ++s) {
    float x[8];
    *(f32x4*)x       = *(const f32x4*)(ap + s * 32);
    *(f32x4*)(x + 4) = *(const f32x4*)(ap + s * 32 + 4);
    split8(x, ah[s], al[s]);
  }
  #pragma unroll
  for (int ntile = 0; ntile < 4; ++ntile) {
    const int jcol = n0 + ntile * 16 + l15;
    f32x4 c0 = {0.f, 0.f, 0.f, 0.f}, c1 = c0, c2 = c0;
    #pragma unroll
    for (int s = 0; s < 4; ++s) {
      short8 bh = *(const short8*)(WiH + (size_t)jcol * INP_ + s * 32 + lk * 8);
      short8 bl = *(const short8*)(WiL + (size_t)jcol * INP_ + s * 32 + lk * 8);
      c0 = mfma16(ah[s], bh, c0);
      c1 = mfma16(ah[s], bl, c1);
      c2 = mfma16(al[s], bh, c2);
    }
    #pragma unroll
    for (int q = 0; q < 4; ++q) {
      int m = m0 + lk * 4 + q;
      int b = m >> 9, t = m & 511;
      float v = c0[q] + c1[q] + c2[q] + bsum[jcol] + 0.1f * noise[(size_t)t * REC_ + jcol];
      if (t == 0) v = 0.f;   // r0 = 0
      rOut[(size_t)b * R_STRIDE_B + (size_t)t * REC_ + jcol] = v;
    }
  }
}

// ---------- Phase 2: persistent scan, 64 WGs x 4 autonomous waves ----------
// Wave (wg, w) owns batch rows [16w,16w+16) x cols [16wg,16wg+16).
// The recurrence is independent per batch row -> the 4 batch-slices are 4
// independent 64-wave all-to-alls. No __syncthreads in the loop; per-wave
// flags; all exchange stores sc1 (agent) so the per-step acquire buffer_inv
// can never discard dirty data (there is none).
__global__ __launch_bounds__(256, 1) void rnn_scan(
    const u16* __restrict__ WrH, const u16* __restrict__ WrL,
    float* __restrict__ rOut, u32* __restrict__ rbuf, u32* __restrict__ flags)
{
  const int wg   = blockIdx.x;
  const int tid  = threadIdx.x;
  const int wave = tid >> 6;                 // batch-slice 0..3
  const int lane = tid & 63;
  const int l15  = lane & 15, lk = lane >> 4;
  const int jcol  = wg * 16 + l15;           // owned output column
  const int bbase = wave * 16;
  const int arow  = bbase + l15;             // A-operand batch row this lane loads
  const int brow  = bbase + lk * 4;          // C/D batch row base (q adds 0..3)

  // Preload this wave's Wr column-slice as B-fragments: 32 ksteps x (hi,lo).
  short8 bh[32], bl[32];
  #pragma unroll
  for (int s = 0; s < 32; ++s) {
    const int k = s * 32 + lk * 8;
    bh[s] = *(const short8*)(WrH + (size_t)jcol * REC_ + k);
    bl[s] = *(const short8*)(WrL + (size_t)jcol * REC_ + k);
  }

  u32* myflag = flags + wave * 64 + wg;      // this wave's producer flag
  const u32* pollp = flags + wave * 64 + lane; // lane polls producer `lane`

  float rp[4] = {0.f, 0.f, 0.f, 0.f};
  float drv[4];
  #pragma unroll
  for (int q = 0; q < 4; ++q)                // prefetch drive for t=1
    drv[q] = rOut[(size_t)(brow + q) * R_STRIDE_B + (size_t)REC_ + jcol];

  for (u32 t = 1; t <= NSTEP; ++t) {
    // ---- wait for all 64 producers of this batch-slice to post step t-1 ----
    if (t > 1) {
      u32 v; int guard = 0;
      do {
        v = __hip_atomic_load(pollp, __ATOMIC_RELAXED, __HIP_MEMORY_SCOPE_AGENT);
      } while (__any((int)(v < t - 1)) && ++guard < (1 << 18));
      // acquire: invalidate L1 + (stale) L2 so rbuf/own-line reads are fresh
      __builtin_amdgcn_fence(__ATOMIC_ACQUIRE, "agent");
    }

    // ---- load packed r[t-1] (own 16 batch rows, all k) and do 96 MFMAs ----
    const u32* ap = rbuf + ((t - 1) & 1) * (B_ * REC_) + (size_t)arow * REC_ + lk * 8;
    f32x4 c0 = {0.f, 0.f, 0.f, 0.f}, c1 = c0, c2 = c0;   // 3 independent chains
    #pragma unroll
    for (int s = 0; s < 32; ++s) {
      uint4 pa = *(const uint4*)(ap + s * 32);
      uint4 pb = *(const uint4*)(ap + s * 32 + 4);
      uint4 hw, lw;
      hw.x = (pa.x & 0xffffu) | (pa.y << 16);
      hw.y = (pa.z & 0xffffu) | (pa.w << 16);
      hw.z = (pb.x & 0xffffu) | (pb.y << 16);
      hw.w = (pb.z & 0xffffu) | (pb.w << 16);
      lw.x = (pa.x >> 16) | (pa.y & 0xffff0000u);
      lw.y = (pa.z >> 16) | (pa.w & 0xffff0000u);
      lw.z = (pb.x >> 16) | (pb.y & 0xffff0000u);
      lw.w = (pb.z >> 16) | (pb.w & 0xffff0000u);
      short8 ah = __builtin_bit_cast(short8, hw);
      short8 al = __builtin_bit_cast(short8, lw);
      c0 = mfma16(ah, bh[s], c0);
      c1 = mfma16(ah, bl[s], c1);
      c2 = mfma16(al, bh[s], c2);
    }

    // ---- epilogue: state update + packed exchange stores (critical path) ----
    u32* op = rbuf + (t & 1) * (B_ * REC_);
    float rn[4];
    #pragma unroll
    for (int q = 0; q < 4; ++q) {
      float h = c0[q] + c1[q] + c2[q] + drv[q];
      rn[q] = 0.9f * rp[q] + 0.1f * fmaxf(h, 0.f);
      rp[q] = rn[q];
      u16 hh = bf16h(rn[q]);
      u16 ll = bf16h(rn[q] - bf16f(hh));
      __hip_atomic_store(&op[(size_t)(brow + q) * REC_ + jcol],
                         (u32)hh | ((u32)ll << 16),
                         __ATOMIC_RELAXED, __HIP_MEMORY_SCOPE_AGENT);
    }
    // release: s_waitcnt vmcnt(0) covers ONLY the 4 rbuf stores above
    if (t < NSTEP)
      __hip_atomic_store(myflag, t, __ATOMIC_RELEASE, __HIP_MEMORY_SCOPE_AGENT);
    // off the critical path: fp32 r for the output tensor
    #pragma unroll
    for (int q = 0; q < 4; ++q)
      __hip_atomic_store(&rOut[(size_t)(brow + q) * R_STRIDE_B + (size_t)t * REC_ + jcol],
                         rn[q], __ATOMIC_RELAXED, __HIP_MEMORY_SCOPE_AGENT);
    // prefetch next step's drive (static data) to overlap with the poll
    if (t < NSTEP) {
      #pragma unroll
      for (int q = 0; q < 4; ++q)
        drv[q] = rOut[(size_t)(brow + q) * R_STRIDE_B + (size_t)(t + 1) * REC_ + jcol];
    }
  }
}

// ---------- Phase 3: out = r @ Wo^T + bo (t>=1), out[:,0,:]=0 ----------
__global__ __launch_bounds__(256) void rnn_phase3(
    const float* __restrict__ rIn, const u16* __restrict__ WoH, const u16* __restrict__ WoL,
    const float* __restrict__ bo, float* __restrict__ out)
{
  const int mt = blockIdx.x;                    // 512 m-tiles of 64 rows
  const int tid = threadIdx.x, wave = tid >> 6, lane = tid & 63;
  const int l15 = lane & 15, lk = lane >> 4;
  const int m0 = mt * 64 + wave * 16;
  const int arow = m0 + l15;
  const float* ap = rIn + (size_t)arow * REC_ + lk * 8;

  f32x4 acc[4][3];
  #pragma unroll
  for (int n = 0; n < 4; ++n)
    #pragma unroll
    for (int u = 0; u < 3; ++u) acc[n][u] = (f32x4){0.f, 0.f, 0.f, 0.f};

  for (int s = 0; s < 32; ++s) {
    float x[8];
    *(f32x4*)x       = *(const f32x4*)(ap + s * 32);
    *(f32x4*)(x + 4) = *(const f32x4*)(ap + s * 32 + 4);
    short8 ahh, all_;
    split8(x, ahh, all_);
    #pragma unroll
    for (int n = 0; n < 4; ++n) {
      const int o16 = n * 16 + l15;
      short8 bhv = *(const short8*)(WoH + (size_t)o16 * REC_ + s * 32 + lk * 8);
      short8 blv = *(const short8*)(WoL + (size_t)o16 * REC_ + s * 32 + lk * 8);
      acc[n][0] = mfma16(ahh, bhv, acc[n][0]);
      acc[n][1] = mfma16(ahh, blv, acc[n][1]);
      acc[n][2] = mfma16(all_, bhv, acc[n][2]);
    }
  }
  #pragma unroll
  for (int n = 0; n < 4; ++n) {
    #pragma unroll
    for (int q = 0; q < 4; ++q) {
      int m = m0 + lk * 4 + q;
      int b = m >> 9, t = m & 511;
      int o = n * 16 + l15;
      float v = acc[n][0][q] + acc[n][1][q] + acc[n][2][q] + bo[o];
      if (t == 0) v = 0.f;
      out[(size_t)b * (T_ * OUT_) + (size_t)t * OUT_ + o] = v;
    }
  }
}

extern "C" void kernel_launch(void* const* d_in, const int* in_sizes, int n_in,
                              void* d_out, int out_size, void* d_ws, size_t ws_size,
                              hipStream_t stream) {
  (void)in_sizes; (void)n_in; (void)out_size; (void)ws_size;
  const float* inp   = (const float*)d_in[0];
  const float* noise = (const float*)d_in[1];
  const float* Wi    = (const float*)d_in[2];
  const float* bi    = (const float*)d_in[3];
  const float* Wr    = (const float*)d_in[4];
  const float* br    = (const float*)d_in[5];
  const float* Wo    = (const float*)d_in[6];
  const float* bo    = (const float*)d_in[7];

  float* out  = (float*)d_out;
  float* rOut = out + (size_t)B_ * T_ * OUT_;   // r region of d_out

  char* ws = (char*)d_ws;
  u16* WrH = (u16*)(ws + OFF_WRH);
  u16* WrL = (u16*)(ws + OFF_WRL);
  u16* WiH = (u16*)(ws + OFF_WIH);
  u16* WiL = (u16*)(ws + OFF_WIL);
  u16* WoH = (u16*)(ws + OFF_WOH);
  u16* WoL = (u16*)(ws + OFF_WOL);
  float* bsum = (float*)(ws + OFF_BSUM);
  u32* rbuf  = (u32*)(ws + OFF_RBUF);
  u32* flags = (u32*)(ws + OFF_FLAGS);

  // zero exchange buffers (r0 = 0) + wave flags (ws is poisoned 0xAA)
  hipMemsetAsync(ws + OFF_RBUF, 0, SYNC_BYTES, stream);

  pack_w<<<dim3(4096), dim3(256), 0, stream>>>(Wr, Wi, Wo, bi, br,
                                               WrH, WrL, WiH, WiL, WoH, WoL, bsum);
  rnn_phase1<<<dim3(8192), dim3(256), 0, stream>>>(inp, noise, WiH, WiL, bsum, rOut);
  rnn_scan<<<dim3(64), dim3(256), 0, stream>>>(WrH, WrL, rOut, rbuf, flags);
  rnn_phase3<<<dim3(512), dim3(256), 0, stream>>>(rOut, WoH, WoL, bo, out);
}

// Round 3
// 10047.382 us; speedup vs baseline: 1.0471x; 1.0471x over previous
//
#include <hip/hip_runtime.h>
#include <hip/hip_bf16.h>

typedef unsigned int u32;
typedef unsigned short u16;
typedef unsigned long long u64;
using short8 = __attribute__((ext_vector_type(8))) short;
using f32x4  = __attribute__((ext_vector_type(4))) float;
using u64x2  = __attribute__((ext_vector_type(2))) unsigned long long;

#define B_    64
#define T_    512
#define INP_  128
#define REC_  1024
#define OUT_  64
#define NSTEP 511
#define R_STRIDE_B ((size_t)T_ * REC_)   // 524288 floats per batch in r region

// ---- ws layout (bytes) ----
#define OFF_WRH   0u
#define OFF_WRL   2097152u
#define OFF_WIH   4194304u
#define OFF_WIL   4456448u
#define OFF_WOH   4718592u
#define OFF_WOL   4849664u
#define OFF_BSUM  4980736u
#define OFF_RBUF  4984832u           // u16 hi[2][64][1024] (256KB) + u16 lo[2][64][1024] (256KB)
#define OFF_FLAGS 5509120u           // u32[256] dense (slice*64 + wg)
#define SYNC_BYTES (524288u + 1024u)
#define PLANE_ELEMS (2 * B_ * REC_)  // u16 elems per plane (both parities)

__device__ __forceinline__ u16 bf16h(float x) {
  u32 u = __float_as_uint(x);
  u32 r = (u + 0x7fffu + ((u >> 16) & 1u)) >> 16;
  return (u16)r;
}
__device__ __forceinline__ float bf16f(u16 h) {
  return __uint_as_float(((u32)h) << 16);
}
__device__ __forceinline__ f32x4 mfma16(short8 a, short8 b, f32x4 c) {
  return __builtin_amdgcn_mfma_f32_16x16x32_bf16(a, b, c, 0, 0, 0);
}
__device__ __forceinline__ void split8(const float* x, short8& ah, short8& al) {
  #pragma unroll
  for (int e = 0; e < 8; ++e) {
    u16 h = bf16h(x[e]);
    ah[e] = (short)h;
    al[e] = (short)bf16h(x[e] - bf16f(h));
  }
}
// LLC-direct (bypass L1+L2) stores: no dirty cache lines anywhere in the scan,
// so no buffer_wbl2/buffer_inv is ever needed. Volatile asm keeps mutual order.
__device__ __forceinline__ void st16_llc(u16* p, u16 v) {
  asm volatile("global_store_short %0, %1, off sc0 sc1" :: "v"(p), "v"((u32)v));
}
__device__ __forceinline__ void st32_llc(u32* p, u32 v) {
  asm volatile("global_store_dword %0, %1, off sc0 sc1" :: "v"(p), "v"(v));
}
__device__ __forceinline__ u64 ld64_llc(const u64* p) {
  return __hip_atomic_load(p, __ATOMIC_RELAXED, __HIP_MEMORY_SCOPE_AGENT);
}

// ---------- Phase 0: pack weights into bf16 hi/lo planes ----------
__global__ void pack_w(const float* __restrict__ Wr, const float* __restrict__ Wi,
                       const float* __restrict__ Wo, const float* __restrict__ bi,
                       const float* __restrict__ br,
                       u16* WrH, u16* WrL, u16* WiH, u16* WiL, u16* WoH, u16* WoL,
                       float* bsum) {
  int id = blockIdx.x * 256 + threadIdx.x;
  if (id < REC_ * REC_) { float x = Wr[id]; u16 h = bf16h(x); WrH[id] = h; WrL[id] = bf16h(x - bf16f(h)); }
  if (id < REC_ * INP_) { float x = Wi[id]; u16 h = bf16h(x); WiH[id] = h; WiL[id] = bf16h(x - bf16f(h)); }
  if (id < OUT_ * REC_) { float x = Wo[id]; u16 h = bf16h(x); WoH[id] = h; WoL[id] = bf16h(x - bf16f(h)); }
  if (id < REC_) bsum[id] = bi[id] + br[id];
}

// ---------- Phase 1: drive[b][t][j] -> rOut (in-place in d_out r region) ----------
__global__ __launch_bounds__(256) void rnn_phase1(
    const float* __restrict__ inp, const float* __restrict__ noise,
    const u16* __restrict__ WiH, const u16* __restrict__ WiL,
    const float* __restrict__ bsum, float* __restrict__ rOut)
{
  const int bid = blockIdx.x;          // 8192 = 512 m-tiles * 16 n-tiles
  const int mt = bid >> 4, nt4 = bid & 15;
  const int tid = threadIdx.x, wave = tid >> 6, lane = tid & 63;
  const int l15 = lane & 15, lk = lane >> 4;
  const int m0 = mt * 64 + wave * 16;
  const int n0 = nt4 * 64;
  const int arow = m0 + l15;
  const float* ap = inp + (size_t)arow * INP_ + lk * 8;

  short8 ah[4], al[4];
  #pragma unroll
  for (int s = 0; s < 4; ++s) {
    float x[8];
    *(f32x4*)x       = *(const f32x4*)(ap + s * 32);
    *(f32x4*)(x + 4) = *(const f32x4*)(ap + s * 32 + 4);
    split8(x, ah[s], al[s]);
  }
  #pragma unroll
  for (int ntile = 0; ntile < 4; ++ntile) {
    const int jcol = n0 + ntile * 16 + l15;
    f32x4 c0 = {0.f, 0.f, 0.f, 0.f}, c1 = c0, c2 = c0;
    #pragma unroll
    for (int s = 0; s < 4; ++s) {
      short8 bh = *(const short8*)(WiH + (size_t)jcol * INP_ + s * 32 + lk * 8);
      short8 bl = *(const short8*)(WiL + (size_t)jcol * INP_ + s * 32 + lk * 8);
      c0 = mfma16(ah[s], bh, c0);
      c1 = mfma16(ah[s], bl, c1);
      c2 = mfma16(al[s], bh, c2);
    }
    #pragma unroll
    for (int q = 0; q < 4; ++q) {
      int m = m0 + lk * 4 + q;
      int b = m >> 9, t = m & 511;
      float v = c0[q] + c1[q] + c2[q] + bsum[jcol] + 0.1f * noise[(size_t)t * REC_ + jcol];
      if (t == 0) v = 0.f;   // r0 = 0
      rOut[(size_t)b * R_STRIDE_B + (size_t)t * REC_ + jcol] = v;
    }
  }
}

// ---------- Phase 2: persistent scan, 64 WGs x 4 autonomous waves ----------
// NO fences / cache-maintenance in the loop. Exchange planes are written
// sc0+sc1 (straight to LLC, never dirty) and read via relaxed agent atomic
// loads (bypass L1/L2, always fresh). Release = volatile-asm vmcnt(0) before
// the flag store; acquire = poll data-dependency (in-order issue) + sched
// barrier. Wr fragments pinned to AGPRs so they can never be rematerialized.
__global__ __launch_bounds__(256, 1) void rnn_scan(
    const u16* __restrict__ WrH, const u16* __restrict__ WrL,
    float* __restrict__ rOut, u16* __restrict__ rbufH, u16* __restrict__ rbufL,
    u32* __restrict__ flags)
{
  const int wg   = blockIdx.x;
  const int tid  = threadIdx.x;
  const int wave = tid >> 6;                 // batch-slice 0..3
  const int lane = tid & 63;
  const int l15  = lane & 15, lk = lane >> 4;
  const int jcol  = wg * 16 + l15;           // owned output column
  const int bbase = wave * 16;
  const int arow  = bbase + l15;             // A-operand batch row this lane loads
  const int brow  = bbase + lk * 4;          // C/D batch row base (q adds 0..3)

  // Preload this wave's Wr column-slice: 32 ksteps x (hi,lo) fragments.
  short8 bh[32], bl[32];
  #pragma unroll
  for (int s = 0; s < 32; ++s) {
    const int k = s * 32 + lk * 8;
    bh[s] = *(const short8*)(WrH + (size_t)jcol * REC_ + k);
    bl[s] = *(const short8*)(WrL + (size_t)jcol * REC_ + k);
  }
  // Pin into AGPRs (gfx950 MFMA reads B directly from AGPRs): defs become
  // opaque asm results -> rematerialization of the global loads is impossible.
  #pragma unroll
  for (int s = 0; s < 32; ++s)
    asm volatile("" : "+a"(bh[s]), "+a"(bl[s]));

  u32* myflag = flags + wave * 64 + wg;        // this wave's producer flag
  const u32* pollp = flags + wave * 64 + lane; // lane polls producer `lane`

  float rp[4] = {0.f, 0.f, 0.f, 0.f};
  float drv[4];
  #pragma unroll
  for (int q = 0; q < 4; ++q)                  // prefetch drive for t=1
    drv[q] = rOut[(size_t)(brow + q) * R_STRIDE_B + (size_t)REC_ + jcol];

  for (u32 t = 1; t <= NSTEP; ++t) {
    const u32 rpar = (t - 1) & 1, wpar = t & 1;
    // ---- wait for all 64 producers of this batch-slice to post step t-1 ----
    if (t > 1) {
      u32 v; int guard = 0;
      do {
        v = __hip_atomic_load(pollp, __ATOMIC_RELAXED, __HIP_MEMORY_SCOPE_AGENT);
      } while (__any((int)(v < t - 1)) && ++guard < (1 << 18));
      __builtin_amdgcn_sched_barrier(0);       // nothing moves above the poll
    }

    // ---- load r[t-1] planes (LLC-direct) and run 96 MFMAs, 3 chains ----
    const u64* hp = (const u64*)(rbufH + rpar * (B_ * REC_) + (size_t)arow * REC_) + lk * 2;
    const u64* lp = (const u64*)(rbufL + rpar * (B_ * REC_) + (size_t)arow * REC_) + lk * 2;
    f32x4 c0 = {0.f, 0.f, 0.f, 0.f}, c1 = c0, c2 = c0;
    #pragma unroll
    for (int s = 0; s < 32; ++s) {
      u64x2 hq, lq;
      hq.x = ld64_llc(hp + s * 8);
      hq.y = ld64_llc(hp + s * 8 + 1);
      lq.x = ld64_llc(lp + s * 8);
      lq.y = ld64_llc(lp + s * 8 + 1);
      short8 ah = __builtin_bit_cast(short8, hq);
      short8 al = __builtin_bit_cast(short8, lq);
      c0 = mfma16(ah, bh[s], c0);
      c1 = mfma16(ah, bl[s], c1);
      c2 = mfma16(al, bh[s], c2);
    }

    // ---- epilogue: state update + plane stores (critical path) ----
    u16* hb = rbufH + wpar * (B_ * REC_);
    u16* lb = rbufL + wpar * (B_ * REC_);
    float rn[4];
    #pragma unroll
    for (int q = 0; q < 4; ++q) {
      float h = c0[q] + c1[q] + c2[q] + drv[q];
      rn[q] = 0.9f * rp[q] + 0.1f * fmaxf(h, 0.f);
      rp[q] = rn[q];
      u16 hh = bf16h(rn[q]);
      u16 ll = bf16h(rn[q] - bf16f(hh));
      st16_llc(hb + (size_t)(brow + q) * REC_ + jcol, hh);
      st16_llc(lb + (size_t)(brow + q) * REC_ + jcol, ll);
    }
    if (t < NSTEP) {
      asm volatile("s_waitcnt vmcnt(0)");      // drain plane stores to LLC
      if (lane == 0) st32_llc(myflag, t);      // then publish
    }
    // off the critical path: fp32 r for the output tensor (plain cached
    // stores; flushed by the end-of-kernel release before phase3 runs)
    #pragma unroll
    for (int q = 0; q < 4; ++q)
      rOut[(size_t)(brow + q) * R_STRIDE_B + (size_t)t * REC_ + jcol] = rn[q];
    // prefetch next step's drive (phase1 data, safe to cache) during the poll
    if (t < NSTEP) {
      #pragma unroll
      for (int q = 0; q < 4; ++q)
        drv[q] = rOut[(size_t)(brow + q) * R_STRIDE_B + (size_t)(t + 1) * REC_ + jcol];
    }
  }
}

// ---------- Phase 3: out = r @ Wo^T + bo (t>=1), out[:,0,:]=0 ----------
__global__ __launch_bounds__(256) void rnn_phase3(
    const float* __restrict__ rIn, const u16* __restrict__ WoH, const u16* __restrict__ WoL,
    const float* __restrict__ bo, float* __restrict__ out)
{
  const int mt = blockIdx.x;                    // 512 m-tiles of 64 rows
  const int tid = threadIdx.x, wave = tid >> 6, lane = tid & 63;
  const int l15 = lane & 15, lk = lane >> 4;
  const int m0 = mt * 64 + wave * 16;
  const int arow = m0 + l15;
  const float* ap = rIn + (size_t)arow * REC_ + lk * 8;

  f32x4 acc[4][3];
  #pragma unroll
  for (int n = 0; n < 4; ++n)
    #pragma unroll
    for (int u = 0; u < 3; ++u) acc[n][u] = (f32x4){0.f, 0.f, 0.f, 0.f};

  for (int s = 0; s < 32; ++s) {
    float x[8];
    *(f32x4*)x       = *(const f32x4*)(ap + s * 32);
    *(f32x4*)(x + 4) = *(const f32x4*)(ap + s * 32 + 4);
    short8 ahh, all_;
    split8(x, ahh, all_);
    #pragma unroll
    for (int n = 0; n < 4; ++n) {
      const int o16 = n * 16 + l15;
      short8 bhv = *(const short8*)(WoH + (size_t)o16 * REC_ + s * 32 + lk * 8);
      short8 blv = *(const short8*)(WoL + (size_t)o16 * REC_ + s * 32 + lk * 8);
      acc[n][0] = mfma16(ahh, bhv, acc[n][0]);
      acc[n][1] = mfma16(ahh, blv, acc[n][1]);
      acc[n][2] = mfma16(all_, bhv, acc[n][2]);
    }
  }
  #pragma unroll
  for (int n = 0; n < 4; ++n) {
    #pragma unroll
    for (int q = 0; q < 4; ++q) {
      int m = m0 + lk * 4 + q;
      int b = m >> 9, t = m & 511;
      int o = n * 16 + l15;
      float v = acc[n][0][q] + acc[n][1][q] + acc[n][2][q] + bo[o];
      if (t == 0) v = 0.f;
      out[(size_t)b * (T_ * OUT_) + (size_t)t * OUT_ + o] = v;
    }
  }
}

extern "C" void kernel_launch(void* const* d_in, const int* in_sizes, int n_in,
                              void* d_out, int out_size, void* d_ws, size_t ws_size,
                              hipStream_t stream) {
  (void)in_sizes; (void)n_in; (void)out_size; (void)ws_size;
  const float* inp   = (const float*)d_in[0];
  const float* noise = (const float*)d_in[1];
  const float* Wi    = (const float*)d_in[2];
  const float* bi    = (const float*)d_in[3];
  const float* Wr    = (const float*)d_in[4];
  const float* br    = (const float*)d_in[5];
  const float* Wo    = (const float*)d_in[6];
  const float* bo    = (const float*)d_in[7];

  float* out  = (float*)d_out;
  float* rOut = out + (size_t)B_ * T_ * OUT_;   // r region of d_out

  char* ws = (char*)d_ws;
  u16* WrH = (u16*)(ws + OFF_WRH);
  u16* WrL = (u16*)(ws + OFF_WRL);
  u16* WiH = (u16*)(ws + OFF_WIH);
  u16* WiL = (u16*)(ws + OFF_WIL);
  u16* WoH = (u16*)(ws + OFF_WOH);
  u16* WoL = (u16*)(ws + OFF_WOL);
  float* bsum = (float*)(ws + OFF_BSUM);
  u16* rbufH = (u16*)(ws + OFF_RBUF);
  u16* rbufL = rbufH + PLANE_ELEMS;
  u32* flags = (u32*)(ws + OFF_FLAGS);

  // zero exchange planes (r0 = 0) + wave flags (ws is poisoned 0xAA)
  hipMemsetAsync(ws + OFF_RBUF, 0, SYNC_BYTES, stream);

  pack_w<<<dim3(4096), dim3(256), 0, stream>>>(Wr, Wi, Wo, bi, br,
                                               WrH, WrL, WiH, WiL, WoH, WoL, bsum);
  rnn_phase1<<<dim3(8192), dim3(256), 0, stream>>>(inp, noise, WiH, WiL, bsum, rOut);
  rnn_scan<<<dim3(64), dim3(256), 0, stream>>>(WrH, WrL, rOut, rbufH, rbufL, flags);
  rnn_phase3<<<dim3(512), dim3(256), 0, stream>>>(rOut, WoH, WoL, bo, out);
}

// Round 8
// 5971.643 us; speedup vs baseline: 1.7618x; 1.6825x over previous
//
#include <hip/hip_runtime.h>
#include <hip/hip_bf16.h>

typedef unsigned int u32;
typedef unsigned short u16;
using short8 = __attribute__((ext_vector_type(8))) short;
using f32x4  = __attribute__((ext_vector_type(4))) float;

#define B_    64
#define T_    512
#define INP_  128
#define REC_  1024
#define OUT_  64
#define NSTEP 511
#define R_STRIDE_B ((size_t)T_ * REC_)   // 524288 floats per batch in r region

// ---- ws layout (bytes) ----
#define OFF_WRH   0u
#define OFF_WRL   2097152u
#define OFF_WIH   4194304u
#define OFF_WIL   4456448u
#define OFF_WOH   4718592u
#define OFF_WOL   4849664u
#define OFF_BSUM  4980736u
#define OFF_RBUF  4984832u   // [parity][row 64][plane 2][1024 u16] = 512 KiB
#define OFF_FLAGS 5509120u   // u32[256] dense (slice*64 + wg)
#define SYNC_BYTES (524288u + 1024u)
#define RB_PAR 262144u       // bytes per parity slice (64 rows * 4096 B)

__device__ __forceinline__ u16 bf16h(float x) {
  u32 u = __float_as_uint(x);
  u32 r = (u + 0x7fffu + ((u >> 16) & 1u)) >> 16;
  return (u16)r;
}
__device__ __forceinline__ float bf16f(u16 h) {
  return __uint_as_float(((u32)h) << 16);
}
__device__ __forceinline__ f32x4 mfma16(short8 a, short8 b, f32x4 c) {
  return __builtin_amdgcn_mfma_f32_16x16x32_bf16(a, b, c, 0, 0, 0);
}
__device__ __forceinline__ void split8(const float* x, short8& ah, short8& al) {
  #pragma unroll
  for (int e = 0; e < 8; ++e) {
    u16 h = bf16h(x[e]);
    ah[e] = (short)h;
    al[e] = (short)bf16h(x[e] - bf16f(h));
  }
}

// ---------- Phase 0: pack weights into bf16 hi/lo planes ----------
__global__ void pack_w(const float* __restrict__ Wr, const float* __restrict__ Wi,
                       const float* __restrict__ Wo, const float* __restrict__ bi,
                       const float* __restrict__ br,
                       u16* WrH, u16* WrL, u16* WiH, u16* WiL, u16* WoH, u16* WoL,
                       float* bsum) {
  int id = blockIdx.x * 256 + threadIdx.x;
  if (id < REC_ * REC_) { float x = Wr[id]; u16 h = bf16h(x); WrH[id] = h; WrL[id] = bf16h(x - bf16f(h)); }
  if (id < REC_ * INP_) { float x = Wi[id]; u16 h = bf16h(x); WiH[id] = h; WiL[id] = bf16h(x - bf16f(h)); }
  if (id < OUT_ * REC_) { float x = Wo[id]; u16 h = bf16h(x); WoH[id] = h; WoL[id] = bf16h(x - bf16f(h)); }
  if (id < REC_) bsum[id] = bi[id] + br[id];
}

// ---------- Phase 1: drive[b][t][j] -> rOut (in-place in d_out r region) ----------
__global__ __launch_bounds__(256) void rnn_phase1(
    const float* __restrict__ inp, const float* __restrict__ noise,
    const u16* __restrict__ WiH, const u16* __restrict__ WiL,
    const float* __restrict__ bsum, float* __restrict__ rOut)
{
  const int bid = blockIdx.x;          // 8192 = 512 m-tiles * 16 n-tiles
  const int mt = bid >> 4, nt4 = bid & 15;
  const int tid = threadIdx.x, wave = tid >> 6, lane = tid & 63;
  const int l15 = lane & 15, lk = lane >> 4;
  const int m0 = mt * 64 + wave * 16;
  const int n0 = nt4 * 64;
  const int arow = m0 + l15;
  const float* ap = inp + (size_t)arow * INP_ + lk * 8;

  short8 ah[4], al[4];
  #pragma unroll
  for (int s = 0; s < 4; ++s) {
    float x[8];
    *(f32x4*)x       = *(const f32x4*)(ap + s * 32);
    *(f32x4*)(x + 4) = *(const f32x4*)(ap + s * 32 + 4);
    split8(x, ah[s], al[s]);
  }
  #pragma unroll
  for (int ntile = 0; ntile < 4; ++ntile) {
    const int jcol = n0 + ntile * 16 + l15;
    f32x4 c0 = {0.f, 0.f, 0.f, 0.f}, c1 = c0, c2 = c0;
    #pragma unroll
    for (int s = 0; s < 4; ++s) {
      short8 bh = *(const short8*)(WiH + (size_t)jcol * INP_ + s * 32 + lk * 8);
      short8 bl = *(const short8*)(WiL + (size_t)jcol * INP_ + s * 32 + lk * 8);
      c0 = mfma16(ah[s], bh, c0);
      c1 = mfma16(ah[s], bl, c1);
      c2 = mfma16(al[s], bh, c2);
    }
    #pragma unroll
    for (int q = 0; q < 4; ++q) {
      int m = m0 + lk * 4 + q;
      int b = m >> 9, t = m & 511;
      float v = c0[q] + c1[q] + c2[q] + bsum[jcol] + 0.1f * noise[(size_t)t * REC_ + jcol];
      if (t == 0) v = 0.f;   // r0 = 0
      rOut[(size_t)b * R_STRIDE_B + (size_t)t * REC_ + jcol] = v;
    }
  }
}

// ---------- Phase 2: persistent scan, hand-counted vmem pipeline ----------
// A-loads: volatile asm global_load_dwordx4 sc0 sc1 (bypass L1/L2, fixed
// issue order), consumed via s_waitcnt vmcnt(N) asms that THREAD the loaded
// fragments through "+v" operands (MFMA data-depends on the wait). B-frags
// live in LDS (compiler-managed lgkmcnt). No fences, no atomic data loads.
// vmcnt ledger (in-order counter): at wait(s) issued = 34+2s loads for
// s<=14 (N=32), 68 at s=15 (N=36, incl. 4 drive loads), then N=66-2s.
// Compiler-inserted vmem ops can only make each wait MORE conservative.
// Max outstanding ~47 < 63 (vmcnt field limit).

#define AISSUE(S)                                                              \
  asm volatile("global_load_dwordx4 %0, %1, off offset:%c2 sc0 sc1"            \
               : "=v"(Ah[S]) : "v"(abase), "n"((S) * 64));                     \
  asm volatile("global_load_dwordx4 %0, %1, off offset:%c2 sc0 sc1"            \
               : "=v"(Al[S]) : "v"(abase), "n"(2048 + (S) * 64));

#define KSTEP(S, NW)                                                           \
  {                                                                            \
    if constexpr ((S) < 16) {                                                  \
      asm volatile("global_load_dwordx4 %0, %1, off offset:%c2 sc0 sc1"        \
                   : "=v"(Ah[(S) + 16]) : "v"(abase), "n"(((S) + 16) * 64));   \
      asm volatile("global_load_dwordx4 %0, %1, off offset:%c2 sc0 sc1"        \
                   : "=v"(Al[(S) + 16]) : "v"(abase), "n"(2048 + ((S) + 16) * 64)); \
    }                                                                          \
    if constexpr ((S) == 15) {                                                 \
      asm volatile("global_load_dword %0, %1, off" : "=v"(nd0) : "v"(dp0));    \
      asm volatile("global_load_dword %0, %1, off" : "=v"(nd1) : "v"(dp1));    \
      asm volatile("global_load_dword %0, %1, off" : "=v"(nd2) : "v"(dp2));    \
      asm volatile("global_load_dword %0, %1, off" : "=v"(nd3) : "v"(dp3));    \
    }                                                                          \
    asm volatile("s_waitcnt vmcnt(%c2)"                                        \
                 : "+v"(Ah[S]), "+v"(Al[S]) : "n"(NW));                        \
    {                                                                          \
      short8 bhv = *(const short8*)&ldsW[(((S) * 2 + 0) * 64 + lane) * 8];     \
      short8 blv = *(const short8*)&ldsW[(((S) * 2 + 1) * 64 + lane) * 8];     \
      c0 = mfma16(Ah[S], bhv, c0);                                             \
      c1 = mfma16(Ah[S], blv, c1);                                             \
      c2 = mfma16(Al[S], bhv, c2);                                             \
    }                                                                          \
  }

#define EPI(Q, DCV)                                                            \
  {                                                                            \
    float h = c0[Q] + c1[Q] + c2[Q] + (DCV);                                   \
    float rn = 0.9f * rp##Q + 0.1f * fmaxf(h, 0.f);                            \
    rp##Q = rn;                                                                \
    u16 hh = bf16h(rn);                                                        \
    u16 ll = bf16h(rn - bf16f(hh));                                            \
    char* sb = stbase + (Q) * 4096;                                            \
    asm volatile("global_store_short %0, %1, off sc0 sc1"                      \
                 :: "v"(sb), "v"((u32)hh));                                    \
    asm volatile("global_store_short %0, %1, off offset:2048 sc0 sc1"          \
                 :: "v"(sb), "v"((u32)ll));                                    \
  }

__global__ __launch_bounds__(256, 1) void rnn_scan(
    const u16* __restrict__ WrH, const u16* __restrict__ WrL,
    float* __restrict__ rOut, char* __restrict__ rbuf, u32* __restrict__ flags)
{
  __shared__ __align__(16) u16 ldsW[32 * 2 * 64 * 8];   // 64 KiB [s][pl][lane][8]

  const int wg = blockIdx.x, tid = threadIdx.x;
  const int wave = tid >> 6, lane = tid & 63;
  const int l15 = lane & 15, lk = lane >> 4;
  const int jcol = wg * 16 + l15;        // owned output column
  const int bbase = wave * 16;
  const int arow = bbase + l15;          // A-operand batch row this lane loads
  const int brow = bbase + lk * 4;       // C/D batch row base (q adds 0..3)

  // stage the WG's Wr slice into LDS (identical for all 4 waves: jcol has no
  // wave dependence). 256 threads x 16 frags of 16 B each.
  {
    const int ln = tid & 63, sblk = tid >> 6;
    const int jc = wg * 16 + (ln & 15), kk = (ln >> 4) * 8;
    #pragma unroll
    for (int s2 = 0; s2 < 8; ++s2) {
      const int s = sblk * 8 + s2;
      *(short8*)&ldsW[((s * 2 + 0) * 64 + ln) * 8] =
          *(const short8*)(WrH + (size_t)jc * REC_ + s * 32 + kk);
      *(short8*)&ldsW[((s * 2 + 1) * 64 + ln) * 8] =
          *(const short8*)(WrL + (size_t)jc * REC_ + s * 32 + kk);
    }
  }
  __syncthreads();

  u32* myflag = flags + wave * 64 + wg;        // this wave's producer flag
  const u32* pollp = flags + wave * 64 + lane; // lane polls producer `lane`

  float rp0 = 0.f, rp1 = 0.f, rp2 = 0.f, rp3 = 0.f;
  float dc0 = 0.f, dc1 = 0.f, dc2 = 0.f, dc3 = 0.f;
  float nd0 = 0.f, nd1 = 0.f, nd2 = 0.f, nd3 = 0.f;

  { // drive prefetch for t=1, drained before the loop
    const float* p0 = rOut + (size_t)(brow + 0) * R_STRIDE_B + REC_ + jcol;
    const float* p1 = rOut + (size_t)(brow + 1) * R_STRIDE_B + REC_ + jcol;
    const float* p2 = rOut + (size_t)(brow + 2) * R_STRIDE_B + REC_ + jcol;
    const float* p3 = rOut + (size_t)(brow + 3) * R_STRIDE_B + REC_ + jcol;
    asm volatile("global_load_dword %0, %1, off" : "=v"(dc0) : "v"(p0));
    asm volatile("global_load_dword %0, %1, off" : "=v"(dc1) : "v"(p1));
    asm volatile("global_load_dword %0, %1, off" : "=v"(dc2) : "v"(p2));
    asm volatile("global_load_dword %0, %1, off" : "=v"(dc3) : "v"(p3));
    asm volatile("s_waitcnt vmcnt(0)"
                 : "+v"(dc0), "+v"(dc1), "+v"(dc2), "+v"(dc3));
  }

  for (u32 t = 1; t <= NSTEP; ++t) {
    const u32 rpar = (t - 1) & 1, wpar = t & 1;

    if (t > 1) {
      u32 v; int guard = 0;
      do {
        v = __hip_atomic_load(pollp, __ATOMIC_RELAXED, __HIP_MEMORY_SCOPE_AGENT);
      } while (__any((int)(v < t - 1)) && ++guard < (1 << 20));
      __builtin_amdgcn_sched_barrier(0);   // nothing crosses above the poll
    }

    const char* abase = rbuf + rpar * RB_PAR + (size_t)arow * 4096 + lk * 16;
    const u32 tn = (t < NSTEP) ? (t + 1) : (u32)NSTEP;  // clamp: value unused at t=NSTEP
    const float* dp0 = rOut + (size_t)(brow + 0) * R_STRIDE_B + (size_t)tn * REC_ + jcol;
    const float* dp1 = rOut + (size_t)(brow + 1) * R_STRIDE_B + (size_t)tn * REC_ + jcol;
    const float* dp2 = rOut + (size_t)(brow + 2) * R_STRIDE_B + (size_t)tn * REC_ + jcol;
    const float* dp3 = rOut + (size_t)(brow + 3) * R_STRIDE_B + (size_t)tn * REC_ + jcol;

    short8 Ah[32], Al[32];
    f32x4 c0 = {0.f, 0.f, 0.f, 0.f}, c1 = c0, c2 = c0;

    AISSUE(0)  AISSUE(1)  AISSUE(2)  AISSUE(3)
    AISSUE(4)  AISSUE(5)  AISSUE(6)  AISSUE(7)
    AISSUE(8)  AISSUE(9)  AISSUE(10) AISSUE(11)
    AISSUE(12) AISSUE(13) AISSUE(14) AISSUE(15)

    KSTEP(0, 32)  KSTEP(1, 32)  KSTEP(2, 32)  KSTEP(3, 32)
    KSTEP(4, 32)  KSTEP(5, 32)  KSTEP(6, 32)  KSTEP(7, 32)
    KSTEP(8, 32)  KSTEP(9, 32)  KSTEP(10, 32) KSTEP(11, 32)
    KSTEP(12, 32) KSTEP(13, 32) KSTEP(14, 32) KSTEP(15, 36)
    KSTEP(16, 34) KSTEP(17, 32) KSTEP(18, 30) KSTEP(19, 28)
    KSTEP(20, 26) KSTEP(21, 24) KSTEP(22, 22) KSTEP(23, 20)
    KSTEP(24, 18) KSTEP(25, 16) KSTEP(26, 14) KSTEP(27, 12)
    KSTEP(28, 10) KSTEP(29, 8)  KSTEP(30, 6)  KSTEP(31, 4)

    // drain drive loads for t+1 (threaded: copies below depend on this)
    asm volatile("s_waitcnt vmcnt(0)"
                 : "+v"(nd0), "+v"(nd1), "+v"(nd2), "+v"(nd3));

    char* stbase = rbuf + wpar * RB_PAR + (size_t)brow * 4096 + (size_t)jcol * 2;
    float rnv[4];
    EPI(0, dc0) EPI(1, dc1) EPI(2, dc2) EPI(3, dc3)
    rnv[0] = rp0; rnv[1] = rp1; rnv[2] = rp2; rnv[3] = rp3;

    asm volatile("s_waitcnt vmcnt(0)");    // rbuf exchange stores at LLC
    if (t < NSTEP && lane == 0)
      asm volatile("global_store_dword %0, %1, off sc0 sc1" :: "v"(myflag), "v"(t));

    // off the handshake path: fp32 r for the output tensor (cached stores,
    // flushed by end-of-dispatch agent release before phase3 — mechanism
    // empirically validated by R2/R3 passing with phase1->scan plain stores)
    #pragma unroll
    for (int q = 0; q < 4; ++q)
      rOut[(size_t)(brow + q) * R_STRIDE_B + (size_t)t * REC_ + jcol] = rnv[q];

    dc0 = nd0; dc1 = nd1; dc2 = nd2; dc3 = nd3;
  }
}

// ---------- Phase 3: out = r @ Wo^T + bo (t>=1), out[:,0,:]=0 ----------
__global__ __launch_bounds__(256) void rnn_phase3(
    const float* __restrict__ rIn, const u16* __restrict__ WoH, const u16* __restrict__ WoL,
    const float* __restrict__ bo, float* __restrict__ out)
{
  const int mt = blockIdx.x;                    // 512 m-tiles of 64 rows
  const int tid = threadIdx.x, wave = tid >> 6, lane = tid & 63;
  const int l15 = lane & 15, lk = lane >> 4;
  const int m0 = mt * 64 + wave * 16;
  const int arow = m0 + l15;
  const float* ap = rIn + (size_t)arow * REC_ + lk * 8;

  f32x4 acc[4][3];
  #pragma unroll
  for (int n = 0; n < 4; ++n)
    #pragma unroll
    for (int u = 0; u < 3; ++u) acc[n][u] = (f32x4){0.f, 0.f, 0.f, 0.f};

  for (int s = 0; s < 32; ++s) {
    float x[8];
    *(f32x4*)x       = *(const f32x4*)(ap + s * 32);
    *(f32x4*)(x + 4) = *(const f32x4*)(ap + s * 32 + 4);
    short8 ahh, all_;
    split8(x, ahh, all_);
    #pragma unroll
    for (int n = 0; n < 4; ++n) {
      const int o16 = n * 16 + l15;
      short8 bhv = *(const short8*)(WoH + (size_t)o16 * REC_ + s * 32 + lk * 8);
      short8 blv = *(const short8*)(WoL + (size_t)o16 * REC_ + s * 32 + lk * 8);
      acc[n][0] = mfma16(ahh, bhv, acc[n][0]);
      acc[n][1] = mfma16(ahh, blv, acc[n][1]);
      acc[n][2] = mfma16(all_, bhv, acc[n][2]);
    }
  }
  #pragma unroll
  for (int n = 0; n < 4; ++n) {
    #pragma unroll
    for (int q = 0; q < 4; ++q) {
      int m = m0 + lk * 4 + q;
      int b = m >> 9, t = m & 511;
      int o = n * 16 + l15;
      float v = acc[n][0][q] + acc[n][1][q] + acc[n][2][q] + bo[o];
      if (t == 0) v = 0.f;
      out[(size_t)b * (T_ * OUT_) + (size_t)t * OUT_ + o] = v;
    }
  }
}

extern "C" void kernel_launch(void* const* d_in, const int* in_sizes, int n_in,
                              void* d_out, int out_size, void* d_ws, size_t ws_size,
                              hipStream_t stream) {
  (void)in_sizes; (void)n_in; (void)out_size; (void)ws_size;
  const float* inp   = (const float*)d_in[0];
  const float* noise = (const float*)d_in[1];
  const float* Wi    = (const float*)d_in[2];
  const float* bi    = (const float*)d_in[3];
  const float* Wr    = (const float*)d_in[4];
  const float* br    = (const float*)d_in[5];
  const float* Wo    = (const float*)d_in[6];
  const float* bo    = (const float*)d_in[7];

  float* out  = (float*)d_out;
  float* rOut = out + (size_t)B_ * T_ * OUT_;   // r region of d_out

  char* ws = (char*)d_ws;
  u16* WrH = (u16*)(ws + OFF_WRH);
  u16* WrL = (u16*)(ws + OFF_WRL);
  u16* WiH = (u16*)(ws + OFF_WIH);
  u16* WiL = (u16*)(ws + OFF_WIL);
  u16* WoH = (u16*)(ws + OFF_WOH);
  u16* WoL = (u16*)(ws + OFF_WOL);
  float* bsum = (float*)(ws + OFF_BSUM);
  char* rbuf  = ws + OFF_RBUF;
  u32* flags = (u32*)(ws + OFF_FLAGS);

  // zero exchange buffer (r0 = 0) + wave flags (ws is poisoned 0xAA)
  hipMemsetAsync(ws + OFF_RBUF, 0, SYNC_BYTES, stream);

  pack_w<<<dim3(4096), dim3(256), 0, stream>>>(Wr, Wi, Wo, bi, br,
                                               WrH, WrL, WiH, WiL, WoH, WoL, bsum);
  rnn_phase1<<<dim3(8192), dim3(256), 0, stream>>>(inp, noise, WiH, WiL, bsum, rOut);
  rnn_scan<<<dim3(64), dim3(256), 0, stream>>>(WrH, WrL, rOut, rbuf, flags);
  rnn_phase3<<<dim3(512), dim3(256), 0, stream>>>(rOut, WoH, WoL, bo, out);
}